// Round 1
// baseline (173.506 us; speedup 1.0000x reference)
//
#include <hip/hip_runtime.h>

// Problem constants (fixed by reference)
#define D_DIRS 1024
#define P_PTS  256
#define R_RANK 64
#define K_SUB  1024

// Workspace layout in floats:
//   a[D][R]            @ 0          (65536 floats, 256 KiB)
//   b[D][R]            @ 65536      (65536 floats, 256 KiB)
//   Mpart[32][64][64]  @ 131072     (131072 floats, 512 KiB)
// total 1 MiB
#define WS_A 0
#define WS_B (D_DIRS * R_RANK)
#define WS_M (2 * D_DIRS * R_RANK)
#define NB_B 32
#define DCHUNK (D_DIRS / NB_B) // 32

// ---------------------------------------------------------------------------
// Kernel 1: p-reduction.  a[d,r] = sum_p atten[d,p,r]; b likewise.
// One block per d. Thread t: rq = t&15 (float4 group of r), pg = t>>4.
// Wave reads 4 consecutive p-rows of 64 floats = 1 KiB contiguous per instr.
// ---------------------------------------------------------------------------
__global__ __launch_bounds__(256) void k_reduce_p(const float* __restrict__ atten,
                                                  const float* __restrict__ rad,
                                                  float* __restrict__ ws) {
    const int d  = blockIdx.x;
    const int t  = threadIdx.x;
    const int rq = t & 15;   // which float4 of the 16 covering R=64
    const int pg = t >> 4;   // p-group 0..15

    const float4* A4 = (const float4*)atten + (size_t)d * (P_PTS * R_RANK / 4);
    const float4* B4 = (const float4*)rad   + (size_t)d * (P_PTS * R_RANK / 4);

    float4 sa = make_float4(0.f, 0.f, 0.f, 0.f);
    float4 sb = make_float4(0.f, 0.f, 0.f, 0.f);
#pragma unroll
    for (int k = 0; k < 16; ++k) {
        const int p   = pg + (k << 4);
        const int idx = p * 16 + rq;
        const float4 va = A4[idx];
        const float4 vb = B4[idx];
        sa.x += va.x; sa.y += va.y; sa.z += va.z; sa.w += va.w;
        sb.x += vb.x; sb.y += vb.y; sb.z += vb.z; sb.w += vb.w;
    }

    __shared__ float4 ra[16][16];
    __shared__ float4 rb[16][16];
    ra[pg][rq] = sa;
    rb[pg][rq] = sb;
    __syncthreads();
#pragma unroll
    for (int s = 8; s >= 1; s >>= 1) {
        if (pg < s) {
            float4 xa = ra[pg + s][rq], ya = ra[pg][rq];
            ya.x += xa.x; ya.y += xa.y; ya.z += xa.z; ya.w += xa.w;
            ra[pg][rq] = ya;
            float4 xb = rb[pg + s][rq], yb = rb[pg][rq];
            yb.x += xb.x; yb.y += xb.y; yb.z += xb.z; yb.w += xb.w;
            rb[pg][rq] = yb;
        }
        __syncthreads();
    }
    if (t < 16) {
        float4* a4 = (float4*)(ws + WS_A);
        float4* b4 = (float4*)(ws + WS_B);
        a4[d * 16 + t] = ra[0][t];
        b4[d * 16 + t] = rb[0][t];
    }
}

// ---------------------------------------------------------------------------
// Kernel 2: partial M.  Block bb covers d in [bb*32, bb*32+32), all (r,r').
// Thread t: c = t&63 is r', wave-group wg = t>>6 gives 16 rows r = wg*16+i.
// a-row reads are wave-uniform (broadcast); b reads are stride-1 (2-way, free).
// ---------------------------------------------------------------------------
__global__ __launch_bounds__(256) void k_partial_m(float* __restrict__ ws) {
    const int bb = blockIdx.x;
    const int t  = threadIdx.x;

    __shared__ float sa[DCHUNK * R_RANK]; // 8 KiB
    __shared__ float sb[DCHUNK * R_RANK]; // 8 KiB

    const float4* a4 = (const float4*)(ws + WS_A) + bb * (DCHUNK * R_RANK / 4);
    const float4* b4 = (const float4*)(ws + WS_B) + bb * (DCHUNK * R_RANK / 4);
    float4* sa4 = (float4*)sa;
    float4* sb4 = (float4*)sb;
    sa4[t]       = a4[t];
    sa4[t + 256] = a4[t + 256];
    sb4[t]       = b4[t];
    sb4[t + 256] = b4[t + 256];
    __syncthreads();

    const int c  = t & 63;
    const int wg = t >> 6;

    float acc[16];
#pragma unroll
    for (int i = 0; i < 16; ++i) acc[i] = 0.f;

    for (int dd = 0; dd < DCHUNK; ++dd) {
        const float bv = sb[dd * 64 + c];
        const float4* ar = (const float4*)&sa[dd * 64 + wg * 16];
        const float4 a0 = ar[0], a1 = ar[1], a2 = ar[2], a3 = ar[3];
        acc[0]  += a0.x * bv; acc[1]  += a0.y * bv; acc[2]  += a0.z * bv; acc[3]  += a0.w * bv;
        acc[4]  += a1.x * bv; acc[5]  += a1.y * bv; acc[6]  += a1.z * bv; acc[7]  += a1.w * bv;
        acc[8]  += a2.x * bv; acc[9]  += a2.y * bv; acc[10] += a2.z * bv; acc[11] += a2.w * bv;
        acc[12] += a3.x * bv; acc[13] += a3.y * bv; acc[14] += a3.z * bv; acc[15] += a3.w * bv;
    }

    float* Mp = ws + WS_M + bb * 4096;
#pragma unroll
    for (int i = 0; i < 16; ++i) Mp[(wg * 16 + i) * 64 + c] = acc[i];
}

// ---------------------------------------------------------------------------
// Kernel 3: reduce partials -> M (LDS), then csi[k] = (1/D) F[k] M F[k]^T.
// 16 blocks x 256 threads; block bb owns k in [bb*64, bb*64+64).
// Thread: kl = t&63 (which k), jg = t>>6 (16 r' columns jg*16..+15).
// Fs padded stride 65 -> conflict-free fv reads; Ms stride 68 keeps float4
// alignment, reads are wave-uniform broadcasts.
// ---------------------------------------------------------------------------
__global__ __launch_bounds__(256) void k_csi(const float* __restrict__ ws,
                                             const float* __restrict__ freq,
                                             float* __restrict__ out) {
    const int bb = blockIdx.x;
    const int t  = threadIdx.x;

    __shared__ float Ms[64 * 68];   // ~17 KiB
    __shared__ float Fs[64 * 65];   // ~16.6 KiB
    __shared__ float red[4][64];

    // Phase 1a: sum the 32 partial Ms into LDS.
    const float4* Mp4 = (const float4*)(ws + WS_M);
#pragma unroll
    for (int i = 0; i < 4; ++i) {
        const int idx4 = i * 256 + t; // float4 index in [0,1024)
        float4 s = make_float4(0.f, 0.f, 0.f, 0.f);
#pragma unroll
        for (int g = 0; g < NB_B; ++g) {
            const float4 v = Mp4[g * 1024 + idx4];
            s.x += v.x; s.y += v.y; s.z += v.z; s.w += v.w;
        }
        const int r = idx4 >> 4, c4 = idx4 & 15;
        *(float4*)&Ms[r * 68 + c4 * 4] = s;
    }

    // Phase 1b: load this block's 64-row tile of F into padded LDS.
    const float4* F4 = (const float4*)freq + bb * 1024;
#pragma unroll
    for (int i = 0; i < 4; ++i) {
        const int idx4 = i * 256 + t;
        const float4 v = F4[idx4];
        const int row = idx4 >> 4, c4 = idx4 & 15;
        Fs[row * 65 + c4 * 4 + 0] = v.x;
        Fs[row * 65 + c4 * 4 + 1] = v.y;
        Fs[row * 65 + c4 * 4 + 2] = v.z;
        Fs[row * 65 + c4 * 4 + 3] = v.w;
    }
    __syncthreads();

    // Phase 2: quadratic form.
    const int kl = t & 63;
    const int jg = t >> 6;

    float h[16];
#pragma unroll
    for (int j = 0; j < 16; ++j) h[j] = 0.f;

    for (int r = 0; r < 64; ++r) {
        const float fv = Fs[kl * 65 + r];
        const float4* mr = (const float4*)&Ms[r * 68 + jg * 16];
        const float4 m0 = mr[0], m1 = mr[1], m2 = mr[2], m3 = mr[3];
        h[0]  += fv * m0.x; h[1]  += fv * m0.y; h[2]  += fv * m0.z; h[3]  += fv * m0.w;
        h[4]  += fv * m1.x; h[5]  += fv * m1.y; h[6]  += fv * m1.z; h[7]  += fv * m1.w;
        h[8]  += fv * m2.x; h[9]  += fv * m2.y; h[10] += fv * m2.z; h[11] += fv * m2.w;
        h[12] += fv * m3.x; h[13] += fv * m3.y; h[14] += fv * m3.z; h[15] += fv * m3.w;
    }

    float part = 0.f;
#pragma unroll
    for (int j = 0; j < 16; ++j) part += h[j] * Fs[kl * 65 + jg * 16 + j];

    red[jg][kl] = part;
    __syncthreads();
    if (t < 64) {
        out[bb * 64 + t] =
            (red[0][t] + red[1][t] + red[2][t] + red[3][t]) * (1.0f / (float)D_DIRS);
    }
}

extern "C" void kernel_launch(void* const* d_in, const int* in_sizes, int n_in,
                              void* d_out, int out_size, void* d_ws, size_t ws_size,
                              hipStream_t stream) {
    const float* atten = (const float*)d_in[0]; // (D,P,R)
    const float* rad   = (const float*)d_in[1]; // (D,P,R)
    const float* freq  = (const float*)d_in[2]; // (K,R)
    float* out = (float*)d_out;                 // (K,)
    float* ws  = (float*)d_ws;                  // needs 1 MiB

    k_reduce_p<<<D_DIRS, 256, 0, stream>>>(atten, rad, ws);
    k_partial_m<<<NB_B, 256, 0, stream>>>(ws);
    k_csi<<<16, 256, 0, stream>>>(ws, freq, out);
}

// Round 2
// 157.403 us; speedup vs baseline: 1.1023x; 1.1023x over previous
//
#include <hip/hip_runtime.h>

// Problem constants (fixed by reference)
#define D_DIRS 1024
#define P_PTS  256
#define R_RANK 64
#define K_SUB  1024

// Workspace layout in floats (1 MiB total — proven to fit in R1):
//   a[D][R]            @ 0          (65536 floats)   -- consumed by k_partial_m
//   b[D][R]            @ 65536      (65536 floats)
//   Mpart[32][64][64]  @ 131072     (131072 floats)
//   Msum[64][64]       @ 0          (4096 floats)    -- OVERLAPS a; written by
//                                    k_reduce_m strictly after k_partial_m read a.
#define WS_A 0
#define WS_B (D_DIRS * R_RANK)
#define WS_M (2 * D_DIRS * R_RANK)
#define WS_MSUM 0
#define NB_B 32
#define DCHUNK (D_DIRS / NB_B) // 32

// ---------------------------------------------------------------------------
// Kernel 1: p-reduction.  a[d,r] = sum_p atten[d,p,r]; b likewise.
// One block of 512 threads per d -> 8 waves/block, 4 blocks/CU = 32 waves/CU
// (R1's 256-thread version capped at 16 waves/CU, occupancy 28%).
// Thread t: rq = t&15 (float4 group of r), pg = t>>4 (0..31).
// Wave reads 4 consecutive p-rows of 256 B = 1 KiB contiguous per instr.
// ---------------------------------------------------------------------------
__global__ __launch_bounds__(512) void k_reduce_p(const float* __restrict__ atten,
                                                  const float* __restrict__ rad,
                                                  float* __restrict__ ws) {
    const int d  = blockIdx.x;
    const int t  = threadIdx.x;
    const int rq = t & 15;   // which float4 of the 16 covering R=64
    const int pg = t >> 4;   // p-group 0..31

    const float4* A4 = (const float4*)atten + (size_t)d * (P_PTS * R_RANK / 4);
    const float4* B4 = (const float4*)rad   + (size_t)d * (P_PTS * R_RANK / 4);

    float4 sa = make_float4(0.f, 0.f, 0.f, 0.f);
    float4 sb = make_float4(0.f, 0.f, 0.f, 0.f);
#pragma unroll
    for (int k = 0; k < 8; ++k) {
        const int p   = pg + (k << 5);
        const int idx = p * 16 + rq;
        const float4 va = A4[idx];
        const float4 vb = B4[idx];
        sa.x += va.x; sa.y += va.y; sa.z += va.z; sa.w += va.w;
        sb.x += vb.x; sb.y += vb.y; sb.z += vb.z; sb.w += vb.w;
    }

    __shared__ float4 ra[32][16]; // 8 KiB
    __shared__ float4 rb[32][16]; // 8 KiB
    ra[pg][rq] = sa;
    rb[pg][rq] = sb;
    __syncthreads();
#pragma unroll
    for (int s = 16; s >= 1; s >>= 1) {
        if (pg < s) {
            float4 xa = ra[pg + s][rq], ya = ra[pg][rq];
            ya.x += xa.x; ya.y += xa.y; ya.z += xa.z; ya.w += xa.w;
            ra[pg][rq] = ya;
            float4 xb = rb[pg + s][rq], yb = rb[pg][rq];
            yb.x += xb.x; yb.y += xb.y; yb.z += xb.z; yb.w += xb.w;
            rb[pg][rq] = yb;
        }
        __syncthreads();
    }
    if (t < 16) {
        float4* a4 = (float4*)(ws + WS_A);
        float4* b4 = (float4*)(ws + WS_B);
        a4[d * 16 + t] = ra[0][t];
        b4[d * 16 + t] = rb[0][t];
    }
}

// ---------------------------------------------------------------------------
// Kernel 2: partial M.  Block bb covers d in [bb*32, bb*32+32), all (r,r').
// Thread t: c = t&63 is r', wave-group wg = t>>6 gives 16 rows r = wg*16+i.
// a-row reads are wave-uniform (broadcast); b reads are stride-1 (2-way, free).
// ---------------------------------------------------------------------------
__global__ __launch_bounds__(256) void k_partial_m(float* __restrict__ ws) {
    const int bb = blockIdx.x;
    const int t  = threadIdx.x;

    __shared__ float sa[DCHUNK * R_RANK]; // 8 KiB
    __shared__ float sb[DCHUNK * R_RANK]; // 8 KiB

    const float4* a4 = (const float4*)(ws + WS_A) + bb * (DCHUNK * R_RANK / 4);
    const float4* b4 = (const float4*)(ws + WS_B) + bb * (DCHUNK * R_RANK / 4);
    float4* sa4 = (float4*)sa;
    float4* sb4 = (float4*)sb;
    sa4[t]       = a4[t];
    sa4[t + 256] = a4[t + 256];
    sb4[t]       = b4[t];
    sb4[t + 256] = b4[t + 256];
    __syncthreads();

    const int c  = t & 63;
    const int wg = t >> 6;

    float acc[16];
#pragma unroll
    for (int i = 0; i < 16; ++i) acc[i] = 0.f;

    for (int dd = 0; dd < DCHUNK; ++dd) {
        const float bv = sb[dd * 64 + c];
        const float4* ar = (const float4*)&sa[dd * 64 + wg * 16];
        const float4 a0 = ar[0], a1 = ar[1], a2 = ar[2], a3 = ar[3];
        acc[0]  += a0.x * bv; acc[1]  += a0.y * bv; acc[2]  += a0.z * bv; acc[3]  += a0.w * bv;
        acc[4]  += a1.x * bv; acc[5]  += a1.y * bv; acc[6]  += a1.z * bv; acc[7]  += a1.w * bv;
        acc[8]  += a2.x * bv; acc[9]  += a2.y * bv; acc[10] += a2.z * bv; acc[11] += a2.w * bv;
        acc[12] += a3.x * bv; acc[13] += a3.y * bv; acc[14] += a3.z * bv; acc[15] += a3.w * bv;
    }

    float* Mp = ws + WS_M + bb * 4096;
#pragma unroll
    for (int i = 0; i < 16; ++i) Mp[(wg * 16 + i) * 64 + c] = acc[i];
}

// ---------------------------------------------------------------------------
// Kernel 3: reduce the 32 partial Ms -> Msum (4096 floats @ ws[0]).
// 4 blocks x 256 threads; thread owns one float4 column, 32 coalesced loads
// (wave reads 1 KiB contiguous per g). 512 KiB read total, done ONCE
// (R1's k_csi re-read all 512 KiB per block = 8 MB).
// ---------------------------------------------------------------------------
__global__ __launch_bounds__(256) void k_reduce_m(float* __restrict__ ws) {
    const int tg = blockIdx.x * 256 + threadIdx.x; // float4 column 0..1023
    const float4* Mp4 = (const float4*)(ws + WS_M);
    float4 s = make_float4(0.f, 0.f, 0.f, 0.f);
#pragma unroll
    for (int g = 0; g < NB_B; ++g) {
        const float4 v = Mp4[g * 1024 + tg];
        s.x += v.x; s.y += v.y; s.z += v.z; s.w += v.w;
    }
    ((float4*)(ws + WS_MSUM))[tg] = s;
}

// ---------------------------------------------------------------------------
// Kernel 4: csi[k] = (1/D) F[k] Msum F[k]^T.
// 16 blocks x 256 threads; block bb owns k in [bb*64, bb*64+64).
// Thread: kl = t&63 (which k), jg = t>>6 (16 r' columns jg*16..+15).
// Fs padded stride 65 -> conflict-free fv reads; Ms stride 68 keeps float4
// alignment, reads are wave-uniform broadcasts.
// ---------------------------------------------------------------------------
__global__ __launch_bounds__(256) void k_csi(const float* __restrict__ ws,
                                             const float* __restrict__ freq,
                                             float* __restrict__ out) {
    const int bb = blockIdx.x;
    const int t  = threadIdx.x;

    __shared__ float Ms[64 * 68];   // ~17 KiB
    __shared__ float Fs[64 * 65];   // ~16.6 KiB
    __shared__ float red[4][64];

    // Phase 1a: load Msum (16 KiB) into padded LDS.
    const float4* M4 = (const float4*)(ws + WS_MSUM);
#pragma unroll
    for (int i = 0; i < 4; ++i) {
        const int idx4 = i * 256 + t; // float4 index in [0,1024)
        const float4 s = M4[idx4];
        const int r = idx4 >> 4, c4 = idx4 & 15;
        *(float4*)&Ms[r * 68 + c4 * 4] = s;
    }

    // Phase 1b: load this block's 64-row tile of F into padded LDS.
    const float4* F4 = (const float4*)freq + bb * 1024;
#pragma unroll
    for (int i = 0; i < 4; ++i) {
        const int idx4 = i * 256 + t;
        const float4 v = F4[idx4];
        const int row = idx4 >> 4, c4 = idx4 & 15;
        Fs[row * 65 + c4 * 4 + 0] = v.x;
        Fs[row * 65 + c4 * 4 + 1] = v.y;
        Fs[row * 65 + c4 * 4 + 2] = v.z;
        Fs[row * 65 + c4 * 4 + 3] = v.w;
    }
    __syncthreads();

    // Phase 2: quadratic form.
    const int kl = t & 63;
    const int jg = t >> 6;

    float h[16];
#pragma unroll
    for (int j = 0; j < 16; ++j) h[j] = 0.f;

    for (int r = 0; r < 64; ++r) {
        const float fv = Fs[kl * 65 + r];
        const float4* mr = (const float4*)&Ms[r * 68 + jg * 16];
        const float4 m0 = mr[0], m1 = mr[1], m2 = mr[2], m3 = mr[3];
        h[0]  += fv * m0.x; h[1]  += fv * m0.y; h[2]  += fv * m0.z; h[3]  += fv * m0.w;
        h[4]  += fv * m1.x; h[5]  += fv * m1.y; h[6]  += fv * m1.z; h[7]  += fv * m1.w;
        h[8]  += fv * m2.x; h[9]  += fv * m2.y; h[10] += fv * m2.z; h[11] += fv * m2.w;
        h[12] += fv * m3.x; h[13] += fv * m3.y; h[14] += fv * m3.z; h[15] += fv * m3.w;
    }

    float part = 0.f;
#pragma unroll
    for (int j = 0; j < 16; ++j) part += h[j] * Fs[kl * 65 + jg * 16 + j];

    red[jg][kl] = part;
    __syncthreads();
    if (t < 64) {
        out[bb * 64 + t] =
            (red[0][t] + red[1][t] + red[2][t] + red[3][t]) * (1.0f / (float)D_DIRS);
    }
}

extern "C" void kernel_launch(void* const* d_in, const int* in_sizes, int n_in,
                              void* d_out, int out_size, void* d_ws, size_t ws_size,
                              hipStream_t stream) {
    const float* atten = (const float*)d_in[0]; // (D,P,R)
    const float* rad   = (const float*)d_in[1]; // (D,P,R)
    const float* freq  = (const float*)d_in[2]; // (K,R)
    float* out = (float*)d_out;                 // (K,)
    float* ws  = (float*)d_ws;                  // needs 1 MiB

    k_reduce_p<<<D_DIRS, 512, 0, stream>>>(atten, rad, ws);
    k_partial_m<<<NB_B, 256, 0, stream>>>(ws);
    k_reduce_m<<<4, 256, 0, stream>>>(ws);
    k_csi<<<16, 256, 0, stream>>>(ws, freq, out);
}

// Round 3
// 150.711 us; speedup vs baseline: 1.1512x; 1.0444x over previous
//
#include <hip/hip_runtime.h>

// Problem constants (fixed by reference)
#define D_DIRS 1024
#define P_PTS  256
#define R_RANK 64
#define K_SUB  1024

typedef float v4f __attribute__((ext_vector_type(4)));

// Workspace layout in floats (1 MiB total — proven to fit):
//   a[D][R]            @ 0          (65536 floats)   -- consumed by k_partial_m
//   b[D][R]            @ 65536      (65536 floats)
//   Mpart[32][64][64]  @ 131072     (131072 floats)
//   Msum[64][64]       @ 0          (4096 floats)    -- OVERLAPS a; written by
//                                    k_reduce_m strictly after k_partial_m read a.
#define WS_A 0
#define WS_B (D_DIRS * R_RANK)
#define WS_M (2 * D_DIRS * R_RANK)
#define WS_MSUM 0
#define NB_B 32
#define DCHUNK (D_DIRS / NB_B) // 32

__device__ __forceinline__ v4f ntload(const v4f* __restrict__ p) {
    return __builtin_nontemporal_load(p);
}

// ---------------------------------------------------------------------------
// Kernel 1: p-reduction.  a[d,r] = sum_p atten[d,p,r]; b likewise.
// One 512-thread block per d. R2 post-mortem: TLP (52% occ) didn't move BW
// (3.1 TB/s) -> per-wave MLP is the lever. This version issues all 16 float4
// loads as independent non-temporal loads before any accumulation (~8x more
// bytes in flight per wave), with a per-block phase swizzle to decorrelate
// channel sweeps across co-resident blocks.
// ---------------------------------------------------------------------------
__global__ __launch_bounds__(512) void k_reduce_p(const float* __restrict__ atten,
                                                  const float* __restrict__ rad,
                                                  float* __restrict__ ws) {
    const int d     = blockIdx.x;
    const int t     = threadIdx.x;
    const int rq    = t & 15;   // which float4 of the 16 covering R=64
    const int pg    = t >> 4;   // p-group 0..31
    const int phase = d & 7;    // channel-decorrelation phase

    const v4f* A4 = (const v4f*)atten + (size_t)d * (P_PTS * R_RANK / 4);
    const v4f* B4 = (const v4f*)rad   + (size_t)d * (P_PTS * R_RANK / 4);

    v4f va[8], vb[8];
#pragma unroll
    for (int k = 0; k < 8; ++k) {
        const int kk  = (k + phase) & 7;
        const int idx = (pg + (kk << 5)) * 16 + rq;
        va[k] = ntload(A4 + idx);
    }
#pragma unroll
    for (int k = 0; k < 8; ++k) {
        const int kk  = (k + phase) & 7;
        const int idx = (pg + (kk << 5)) * 16 + rq;
        vb[k] = ntload(B4 + idx);
    }

    // Pairwise accumulation (keeps dependency chains short).
    v4f sa = (va[0] + va[1]) + (va[2] + va[3]) + ((va[4] + va[5]) + (va[6] + va[7]));
    v4f sb = (vb[0] + vb[1]) + (vb[2] + vb[3]) + ((vb[4] + vb[5]) + (vb[6] + vb[7]));

    __shared__ v4f ra[32][16]; // 8 KiB
    __shared__ v4f rb[32][16]; // 8 KiB
    ra[pg][rq] = sa;
    rb[pg][rq] = sb;
    __syncthreads();
#pragma unroll
    for (int s = 16; s >= 1; s >>= 1) {
        if (pg < s) {
            ra[pg][rq] = ra[pg][rq] + ra[pg + s][rq];
            rb[pg][rq] = rb[pg][rq] + rb[pg + s][rq];
        }
        __syncthreads();
    }
    if (t < 16) {
        v4f* a4 = (v4f*)(ws + WS_A);
        v4f* b4 = (v4f*)(ws + WS_B);
        a4[d * 16 + t] = ra[0][t];
        b4[d * 16 + t] = rb[0][t];
    }
}

// ---------------------------------------------------------------------------
// Kernel 2: partial M.  Block bb covers d in [bb*32, bb*32+32), all (r,r').
// Thread t: c = t&63 is r', wave-group wg = t>>6 gives 16 rows r = wg*16+i.
// a-row reads are wave-uniform (broadcast); b reads are stride-1 (2-way, free).
// ---------------------------------------------------------------------------
__global__ __launch_bounds__(256) void k_partial_m(float* __restrict__ ws) {
    const int bb = blockIdx.x;
    const int t  = threadIdx.x;

    __shared__ float sa[DCHUNK * R_RANK]; // 8 KiB
    __shared__ float sb[DCHUNK * R_RANK]; // 8 KiB

    const float4* a4 = (const float4*)(ws + WS_A) + bb * (DCHUNK * R_RANK / 4);
    const float4* b4 = (const float4*)(ws + WS_B) + bb * (DCHUNK * R_RANK / 4);
    float4* sa4 = (float4*)sa;
    float4* sb4 = (float4*)sb;
    sa4[t]       = a4[t];
    sa4[t + 256] = a4[t + 256];
    sb4[t]       = b4[t];
    sb4[t + 256] = b4[t + 256];
    __syncthreads();

    const int c  = t & 63;
    const int wg = t >> 6;

    float acc[16];
#pragma unroll
    for (int i = 0; i < 16; ++i) acc[i] = 0.f;

    for (int dd = 0; dd < DCHUNK; ++dd) {
        const float bv = sb[dd * 64 + c];
        const float4* ar = (const float4*)&sa[dd * 64 + wg * 16];
        const float4 a0 = ar[0], a1 = ar[1], a2 = ar[2], a3 = ar[3];
        acc[0]  += a0.x * bv; acc[1]  += a0.y * bv; acc[2]  += a0.z * bv; acc[3]  += a0.w * bv;
        acc[4]  += a1.x * bv; acc[5]  += a1.y * bv; acc[6]  += a1.z * bv; acc[7]  += a1.w * bv;
        acc[8]  += a2.x * bv; acc[9]  += a2.y * bv; acc[10] += a2.z * bv; acc[11] += a2.w * bv;
        acc[12] += a3.x * bv; acc[13] += a3.y * bv; acc[14] += a3.z * bv; acc[15] += a3.w * bv;
    }

    float* Mp = ws + WS_M + bb * 4096;
#pragma unroll
    for (int i = 0; i < 16; ++i) Mp[(wg * 16 + i) * 64 + c] = acc[i];
}

// ---------------------------------------------------------------------------
// Kernel 3: reduce the 32 partial Ms -> Msum (4096 floats @ ws[0]).
// 4 blocks x 256 threads; thread owns one float4 column, 32 coalesced loads.
// ---------------------------------------------------------------------------
__global__ __launch_bounds__(256) void k_reduce_m(float* __restrict__ ws) {
    const int tg = blockIdx.x * 256 + threadIdx.x; // float4 column 0..1023
    const float4* Mp4 = (const float4*)(ws + WS_M);
    float4 s = make_float4(0.f, 0.f, 0.f, 0.f);
#pragma unroll
    for (int g = 0; g < NB_B; ++g) {
        const float4 v = Mp4[g * 1024 + tg];
        s.x += v.x; s.y += v.y; s.z += v.z; s.w += v.w;
    }
    ((float4*)(ws + WS_MSUM))[tg] = s;
}

// ---------------------------------------------------------------------------
// Kernel 4: csi[k] = (1/D) F[k] Msum F[k]^T.
// 16 blocks x 256 threads; block bb owns k in [bb*64, bb*64+64).
// Thread: kl = t&63 (which k), jg = t>>6 (16 r' columns jg*16..+15).
// Fs padded stride 65 -> conflict-free fv reads; Ms stride 68 keeps float4
// alignment, reads are wave-uniform broadcasts.
// ---------------------------------------------------------------------------
__global__ __launch_bounds__(256) void k_csi(const float* __restrict__ ws,
                                             const float* __restrict__ freq,
                                             float* __restrict__ out) {
    const int bb = blockIdx.x;
    const int t  = threadIdx.x;

    __shared__ float Ms[64 * 68];   // ~17 KiB
    __shared__ float Fs[64 * 65];   // ~16.6 KiB
    __shared__ float red[4][64];

    // Phase 1a: load Msum (16 KiB) into padded LDS.
    const float4* M4 = (const float4*)(ws + WS_MSUM);
#pragma unroll
    for (int i = 0; i < 4; ++i) {
        const int idx4 = i * 256 + t; // float4 index in [0,1024)
        const float4 s = M4[idx4];
        const int r = idx4 >> 4, c4 = idx4 & 15;
        *(float4*)&Ms[r * 68 + c4 * 4] = s;
    }

    // Phase 1b: load this block's 64-row tile of F into padded LDS.
    const float4* F4 = (const float4*)freq + bb * 1024;
#pragma unroll
    for (int i = 0; i < 4; ++i) {
        const int idx4 = i * 256 + t;
        const float4 v = F4[idx4];
        const int row = idx4 >> 4, c4 = idx4 & 15;
        Fs[row * 65 + c4 * 4 + 0] = v.x;
        Fs[row * 65 + c4 * 4 + 1] = v.y;
        Fs[row * 65 + c4 * 4 + 2] = v.z;
        Fs[row * 65 + c4 * 4 + 3] = v.w;
    }
    __syncthreads();

    // Phase 2: quadratic form.
    const int kl = t & 63;
    const int jg = t >> 6;

    float h[16];
#pragma unroll
    for (int j = 0; j < 16; ++j) h[j] = 0.f;

    for (int r = 0; r < 64; ++r) {
        const float fv = Fs[kl * 65 + r];
        const float4* mr = (const float4*)&Ms[r * 68 + jg * 16];
        const float4 m0 = mr[0], m1 = mr[1], m2 = mr[2], m3 = mr[3];
        h[0]  += fv * m0.x; h[1]  += fv * m0.y; h[2]  += fv * m0.z; h[3]  += fv * m0.w;
        h[4]  += fv * m1.x; h[5]  += fv * m1.y; h[6]  += fv * m1.z; h[7]  += fv * m1.w;
        h[8]  += fv * m2.x; h[9]  += fv * m2.y; h[10] += fv * m2.z; h[11] += fv * m2.w;
        h[12] += fv * m3.x; h[13] += fv * m3.y; h[14] += fv * m3.z; h[15] += fv * m3.w;
    }

    float part = 0.f;
#pragma unroll
    for (int j = 0; j < 16; ++j) part += h[j] * Fs[kl * 65 + jg * 16 + j];

    red[jg][kl] = part;
    __syncthreads();
    if (t < 64) {
        out[bb * 64 + t] =
            (red[0][t] + red[1][t] + red[2][t] + red[3][t]) * (1.0f / (float)D_DIRS);
    }
}

extern "C" void kernel_launch(void* const* d_in, const int* in_sizes, int n_in,
                              void* d_out, int out_size, void* d_ws, size_t ws_size,
                              hipStream_t stream) {
    const float* atten = (const float*)d_in[0]; // (D,P,R)
    const float* rad   = (const float*)d_in[1]; // (D,P,R)
    const float* freq  = (const float*)d_in[2]; // (K,R)
    float* out = (float*)d_out;                 // (K,)
    float* ws  = (float*)d_ws;                  // needs 1 MiB

    k_reduce_p<<<D_DIRS, 512, 0, stream>>>(atten, rad, ws);
    k_partial_m<<<NB_B, 256, 0, stream>>>(ws);
    k_reduce_m<<<4, 256, 0, stream>>>(ws);
    k_csi<<<16, 256, 0, stream>>>(ws, freq, out);
}